// Round 1
// baseline (59.572 us; speedup 1.0000x reference)
//
#include <hip/hip_runtime.h>
#include <hip/hip_bf16.h>

// Tensor-train gather: out[q] = sum_{a,b} g0[0,i0,a] * g1[a,i1,b] * g2[b,i2,0]
// g0: (1,320,16) -> row-major [i0*16 + a]
// g1: (16,320,16) -> [a*320*16 + i1*16 + b] = [a*5120 + i1*16 + b]
// g2: (16,320,1) -> [b*320 + i2]
// 16 lanes cooperate per query; 4 queries per wave64.

__global__ __launch_bounds__(256) void tt_gather_kernel(
    const float* __restrict__ g0,
    const float* __restrict__ g1,
    const float* __restrict__ g2,
    const int* __restrict__ idxs,
    float* __restrict__ out,
    int N)
{
    int tid = blockIdx.x * blockDim.x + threadIdx.x;
    int q = tid >> 4;        // query index
    int b = tid & 15;        // lane's column of the G1 slice / row of g2
    if (q >= N) return;

    const int i0 = idxs[3 * q + 0];
    const int i1 = idxs[3 * q + 1];
    const int i2 = idxs[3 * q + 2];

    const float* __restrict__ g0r = g0 + i0 * 16;          // 16 floats
    const float* __restrict__ g1r = g1 + i1 * 16 + b;      // stride 5120 over a

    float v = 0.0f;
#pragma unroll
    for (int a = 0; a < 16; ++a) {
        v += g0r[a] * g1r[a * 5120];
    }

    float w = v * g2[b * 320 + i2];

    // Reduce across the 16-lane group (aligned within wave64).
#pragma unroll
    for (int off = 8; off >= 1; off >>= 1) {
        w += __shfl_xor(w, off, 64);
    }

    if (b == 0) out[q] = w;
}

extern "C" void kernel_launch(void* const* d_in, const int* in_sizes, int n_in,
                              void* d_out, int out_size, void* d_ws, size_t ws_size,
                              hipStream_t stream) {
    const float* g0 = (const float*)d_in[0];
    const float* g1 = (const float*)d_in[1];
    const float* g2 = (const float*)d_in[2];
    const int* idxs = (const int*)d_in[3];
    float* out = (float*)d_out;

    const int N = in_sizes[3] / 3;       // 8192 queries
    const int threads = N * 16;          // 16 lanes per query
    const int block = 256;
    const int grid = (threads + block - 1) / block;

    tt_gather_kernel<<<grid, block, 0, stream>>>(g0, g1, g2, idxs, out, N);
}